// Round 12
// baseline (107.881 us; speedup 1.0000x reference)
//
#include <hip/hip_runtime.h>

// LatticeGaussian: out = W @ U - U, W[i,j] = exp(-0.5*||ref_i - ref_j||^2)
// N=8192, C=16, D=5, fp32.
//
// R12 == R11 (GPU timeout; MFMA restructure unmeasured; layout re-audited
// by hand this round, no bug found).
// R11: MFMA restructure. Scalar-broadcast structure proved pipe-capacity
// bound at ~50% VALUBusy (R6/R9/R10: VALU floor 27us + LDS-pipe ~= VALU
// demand; three scheduling theories falsified). Move both phases to the
// idle MFMA pipe:
//  - E-tile: one mfma_f32_16x16x32_bf16 computes the FULL exponent
//    log2e*(ri.rj - |ri|^2/2 - |rj|^2/2) per 16x16 tile: K-slots carry a
//    3-term bf16 trunc-split (ah*bh k0-4, ah*bl k5-9, al*bh k10-14,
//    residual ~2^-17) plus bias slots (s2h,s2l)*1 and 1*(a2h,a2l).
//  - w = exp2(E) per lane (4/tile), split hi/lo.
//  - PV: acc += U*W via 3 mfma (Uh*Wh + Uh*Wl + Ul*Wh). Layout transpose
//    avoided by DEFINING the PV k-slot<->j map to match the Et D-frag
//    (lane holds i=l&15, j=4G+q) and pre-packing U accordingly
//    (transposed, j-interleaved, hi/lo) in lg_pre. No LDS anywhere.
// Measured-layout dependency: C/D frag col=l&15, row=(l>>4)*4+reg (m89).
// Within-frag k-permutations cancel (applied identically to A and B).
// Grid: 128 i-chunks(64 i, 4 waves x 16) x NSEG=16 segs = 2048 blocks.
// ws: refB 512KB + Upk 2x256KB + part 8.4MB = 9.4MB (was 33.6 -> less
// poison). Prediction: lg_mfma 10-18us, MfmaUtil>0, total ~70-85us.

#define N_ROWS 8192
#define C_CH   16
#define D_DIM  5
#define TPB    256
#define NSEG   16
#define JPB    (N_ROWS / NSEG)      // 512 j per segment
#define NIB    128                  // i-chunks of 64 (4 waves x 16)
#define ONEBF  0x3F80u              // bf16 1.0

#if __has_builtin(__builtin_amdgcn_exp2f)
#define EXP2(x) __builtin_amdgcn_exp2f(x)
#else
#define EXP2(x) exp2f(x)
#endif

#define LOG2E 1.4426950408889634f

typedef __attribute__((ext_vector_type(8))) short bf16x8;
typedef __attribute__((ext_vector_type(4))) float f32x4;

__device__ __forceinline__ unsigned bhi(float x) {            // bf16 trunc
    return __float_as_uint(x) >> 16;
}
__device__ __forceinline__ float bhif(float x) {              // trunc as f32
    return __uint_as_float(__float_as_uint(x) & 0xFFFF0000u);
}

// ---- pre-kernel: pack refB rows (E A-operand) + U transposed/split ----
__global__ __launch_bounds__(TPB) void lg_pre(const float* __restrict__ U,
                                              const float* __restrict__ ref,
                                              unsigned* __restrict__ refB,
                                              unsigned* __restrict__ uph,
                                              unsigned* __restrict__ upl) {
    const int t = blockIdx.x * TPB + threadIdx.x;
    if (t < N_ROWS) {
        // refB row j=t: 32 bf16 slots = 16 u32.
        float b[D_DIM], r2 = 0.0f;
#pragma unroll
        for (int d = 0; d < D_DIM; ++d) {
            const float r = ref[t * D_DIM + d];
            b[d] = LOG2E * r;
            r2 = fmaf(r, r, r2);
        }
        const float s2 = -0.5f * LOG2E * r2;
        unsigned bh[D_DIM], bl[D_DIM];
#pragma unroll
        for (int d = 0; d < D_DIM; ++d) {
            bh[d] = bhi(b[d]);
            bl[d] = bhi(b[d] - bhif(b[d]));
        }
        const unsigned sh = bhi(s2);
        const unsigned sl = bhi(s2 - bhif(s2));
        unsigned o[16];
        o[0] = bh[0] | (bh[1] << 16);  o[1] = bh[2] | (bh[3] << 16);
        o[2] = bh[4] | (bl[0] << 16);  o[3] = bl[1] | (bl[2] << 16);
        o[4] = bl[3] | (bl[4] << 16);  o[5] = bh[0] | (bh[1] << 16);
        o[6] = bh[2] | (bh[3] << 16);  o[7] = bh[4];             // slot15 = 0
        o[8] = sh | (sl << 16);        o[9] = ONEBF | (ONEBF << 16);
        o[10] = 0; o[11] = 0; o[12] = 0; o[13] = 0; o[14] = 0; o[15] = 0;
        uint4* dst = reinterpret_cast<uint4*>(refB + (size_t)t * 16);
        dst[0] = make_uint4(o[0], o[1], o[2], o[3]);
        dst[1] = make_uint4(o[4], o[5], o[6], o[7]);
        dst[2] = make_uint4(o[8], o[9], o[10], o[11]);
        dst[3] = make_uint4(o[12], o[13], o[14], o[15]);
    } else if (t < N_ROWS + (C_CH * N_ROWS / 2)) {
        // Upk: transposed, j-interleaved, hi/lo split. One u32 (2 bf16) per
        // thread. Row c has 4096 u32.
        const int q = t - N_ROWS;
        const int c = q >> 12;              // 0..15
        const int p = q & 4095;             // u32 index within row
        float u[2], lo[2];
#pragma unroll
        for (int h = 0; h < 2; ++h) {
            const int idx = 2 * p + h;      // packed element position
            const int blk = idx >> 5;       // 32-element block
            const int w32 = idx & 31;
            const int G = w32 >> 3;
            const int e = w32 & 7;
            const int jm = blk * 32 + ((e < 4) ? (G * 4 + e)
                                               : (16 + G * 4 + (e - 4)));
            u[h] = U[(size_t)jm * C_CH + c];
            lo[h] = u[h] - bhif(u[h]);
        }
        uph[(size_t)c * 4096 + p] = bhi(u[0]) | (bhi(u[1]) << 16);
        upl[(size_t)c * 4096 + p] = bhi(lo[0]) | (bhi(lo[1]) << 16);
    }
}

// ---- main kernel: E via MFMA, exp2, PV via MFMA ----
__global__ __launch_bounds__(TPB) void lg_mfma(const float* __restrict__ ref,
                                               const unsigned* __restrict__ refB,
                                               const unsigned* __restrict__ uph,
                                               const unsigned* __restrict__ upl,
                                               float* __restrict__ part) {
    const int ib  = blockIdx.x & (NIB - 1);
    const int seg = blockIdx.x / NIB;
    const int tid = threadIdx.x;
    const int wv  = tid >> 6;
    const int l   = tid & 63;
    const int li  = l & 15;
    const int G   = l >> 4;
    const int i   = ib * 64 + wv * 16 + li;

    // Build the per-lane E B-fragment (i-side), slots k = G*8 + e:
    // k0-4: ah_d   k5-9: ah_d   k10-14: al_d   k15: 0
    // k16,17: ONE,ONE   k18,19: a2h,a2l   k20-31: 0
    float a[D_DIM], r2 = 0.0f;
#pragma unroll
    for (int d = 0; d < D_DIM; ++d) {
        a[d] = ref[i * D_DIM + d];
        r2 = fmaf(a[d], a[d], r2);
    }
    const float a2 = -0.5f * LOG2E * r2;
    unsigned ah[D_DIM], al[D_DIM];
#pragma unroll
    for (int d = 0; d < D_DIM; ++d) {
        ah[d] = bhi(a[d]);
        al[d] = bhi(a[d] - bhif(a[d]));
    }
    const unsigned a2h = bhi(a2);
    const unsigned a2l = bhi(a2 - bhif(a2));

    unsigned c0, c1, c2, c3;
    if (G == 0) {
        c0 = ah[0] | (ah[1] << 16); c1 = ah[2] | (ah[3] << 16);
        c2 = ah[4] | (ah[0] << 16); c3 = ah[1] | (ah[2] << 16);
    } else if (G == 1) {
        c0 = ah[3] | (ah[4] << 16); c1 = al[0] | (al[1] << 16);
        c2 = al[2] | (al[3] << 16); c3 = al[4];
    } else if (G == 2) {
        c0 = ONEBF | (ONEBF << 16); c1 = a2h | (a2l << 16);
        c2 = 0; c3 = 0;
    } else {
        c0 = 0; c1 = 0; c2 = 0; c3 = 0;
    }
    const uint4 bfu = make_uint4(c0, c1, c2, c3);
    const bf16x8 bfrag = __builtin_bit_cast(bf16x8, bfu);

    f32x4 acc = {0.0f, 0.0f, 0.0f, 0.0f};
    const f32x4 zero = {0.0f, 0.0f, 0.0f, 0.0f};

    const uint4* RB = reinterpret_cast<const uint4*>(refB);
    const uint4* UH = reinterpret_cast<const uint4*>(uph);
    const uint4* UL = reinterpret_cast<const uint4*>(upl);

    const int j0 = seg * JPB;
#pragma unroll 2
    for (int js = 0; js < JPB / 32; ++js) {
        const int jb = j0 + js * 32;

        // E A-frags: refB row (jb+li) / (jb+16+li), 16B at G*16.
        const uint4 rb1 = RB[(size_t)(jb + li) * 4 + G];
        const uint4 rb2 = RB[(size_t)(jb + 16 + li) * 4 + G];

        const f32x4 e1 = __builtin_amdgcn_mfma_f32_16x16x32_bf16(
            __builtin_bit_cast(bf16x8, rb1), bfrag, zero, 0, 0, 0);
        const f32x4 e2 = __builtin_amdgcn_mfma_f32_16x16x32_bf16(
            __builtin_bit_cast(bf16x8, rb2), bfrag, zero, 0, 0, 0);

        const float w0 = EXP2(e1[0]);
        const float w1 = EXP2(e1[1]);
        const float w2 = EXP2(e1[2]);
        const float w3 = EXP2(e1[3]);
        const float w4 = EXP2(e2[0]);
        const float w5 = EXP2(e2[1]);
        const float w6 = EXP2(e2[2]);
        const float w7 = EXP2(e2[3]);

        // W hi fragment (bf16 trunc), element order e0..e7 (low half first).
        const unsigned h0 = (__float_as_uint(w1) & 0xFFFF0000u) | (__float_as_uint(w0) >> 16);
        const unsigned h1 = (__float_as_uint(w3) & 0xFFFF0000u) | (__float_as_uint(w2) >> 16);
        const unsigned h2 = (__float_as_uint(w5) & 0xFFFF0000u) | (__float_as_uint(w4) >> 16);
        const unsigned h3 = (__float_as_uint(w7) & 0xFFFF0000u) | (__float_as_uint(w6) >> 16);
        // W lo fragment.
        const float q0 = w0 - bhif(w0), q1 = w1 - bhif(w1);
        const float q2 = w2 - bhif(w2), q3 = w3 - bhif(w3);
        const float q4 = w4 - bhif(w4), q5 = w5 - bhif(w5);
        const float q6 = w6 - bhif(w6), q7 = w7 - bhif(w7);
        const unsigned g0 = (__float_as_uint(q1) & 0xFFFF0000u) | (__float_as_uint(q0) >> 16);
        const unsigned g1 = (__float_as_uint(q3) & 0xFFFF0000u) | (__float_as_uint(q2) >> 16);
        const unsigned g2 = (__float_as_uint(q5) & 0xFFFF0000u) | (__float_as_uint(q4) >> 16);
        const unsigned g3 = (__float_as_uint(q7) & 0xFFFF0000u) | (__float_as_uint(q6) >> 16);

        const bf16x8 wh = __builtin_bit_cast(bf16x8, make_uint4(h0, h1, h2, h3));
        const bf16x8 wl = __builtin_bit_cast(bf16x8, make_uint4(g0, g1, g2, g3));

        // U A-frags (pre-packed to this k<->j map): row c=li, u32x4 index.
        const size_t uidx = (size_t)li * 1024 + (jb >> 3) + G;
        const bf16x8 uh = __builtin_bit_cast(bf16x8, UH[uidx]);
        const bf16x8 ul = __builtin_bit_cast(bf16x8, UL[uidx]);

        acc = __builtin_amdgcn_mfma_f32_16x16x32_bf16(uh, wh, acc, 0, 0, 0);
        acc = __builtin_amdgcn_mfma_f32_16x16x32_bf16(uh, wl, acc, 0, 0, 0);
        acc = __builtin_amdgcn_mfma_f32_16x16x32_bf16(ul, wh, acc, 0, 0, 0);
    }

    // D frag: row = c = G*4+q, col = i = li. part[seg][c][i].
#pragma unroll
    for (int q = 0; q < 4; ++q) {
        part[(size_t)(seg * C_CH + G * 4 + q) * N_ROWS + i] = acc[q];
    }
}

__global__ __launch_bounds__(TPB) void lg_reduce(const float* __restrict__ U,
                                                 const float* __restrict__ part,
                                                 float* __restrict__ out) {
    const int t = blockIdx.x * TPB + threadIdx.x;   // [0, 131072)
    const int i = t & (N_ROWS - 1);
    const int c = t >> 13;
    float s = 0.0f;
#pragma unroll 4
    for (int seg = 0; seg < NSEG; ++seg)
        s += part[(size_t)(seg * C_CH + c) * N_ROWS + i];
    out[(size_t)i * C_CH + c] = s - U[(size_t)i * C_CH + c];
}

// ---- Last-resort fallback (ws too small): init -U + atomics ----
__global__ __launch_bounds__(TPB) void lg_init(const float* __restrict__ U,
                                               float* __restrict__ out) {
    const int idx = blockIdx.x * TPB + threadIdx.x;
    if (idx < N_ROWS * C_CH) out[idx] = -U[idx];
}

__global__ __launch_bounds__(TPB) void lg_main_atomic(const float* __restrict__ U,
                                                      const float* __restrict__ ref,
                                                      float* __restrict__ out) {
    constexpr int NS = 32, JP = N_ROWS / NS, NI = N_ROWS / TPB;
    const int ib = blockIdx.x % NI, sg = blockIdx.x / NI;
    const int i = ib * TPB + threadIdx.x;
    const float r0 = ref[i * D_DIM + 0], r1 = ref[i * D_DIM + 1];
    const float r2 = ref[i * D_DIM + 2], r3 = ref[i * D_DIM + 3];
    const float r4 = ref[i * D_DIM + 4];
    float acc[C_CH];
#pragma unroll
    for (int c = 0; c < C_CH; ++c) acc[c] = 0.0f;
    const float4* __restrict__ U4 = reinterpret_cast<const float4*>(U);
    const int j0 = sg * JP;
#pragma unroll 4
    for (int j = j0; j < j0 + JP; ++j) {
        const float d0 = r0 - ref[j * D_DIM + 0];
        const float d1 = r1 - ref[j * D_DIM + 1];
        const float d2 = r2 - ref[j * D_DIM + 2];
        const float d3 = r3 - ref[j * D_DIM + 3];
        const float d4 = r4 - ref[j * D_DIM + 4];
        float dsq = d0 * d0;
        dsq = fmaf(d1, d1, dsq); dsq = fmaf(d2, d2, dsq);
        dsq = fmaf(d3, d3, dsq); dsq = fmaf(d4, d4, dsq);
        const float w = __expf(-0.5f * dsq);
        const float4 u0 = U4[j * 4 + 0], u1 = U4[j * 4 + 1];
        const float4 u2 = U4[j * 4 + 2], u3 = U4[j * 4 + 3];
        acc[0]  = fmaf(w, u0.x, acc[0]);   acc[1]  = fmaf(w, u0.y, acc[1]);
        acc[2]  = fmaf(w, u0.z, acc[2]);   acc[3]  = fmaf(w, u0.w, acc[3]);
        acc[4]  = fmaf(w, u1.x, acc[4]);   acc[5]  = fmaf(w, u1.y, acc[5]);
        acc[6]  = fmaf(w, u1.z, acc[6]);   acc[7]  = fmaf(w, u1.w, acc[7]);
        acc[8]  = fmaf(w, u2.x, acc[8]);   acc[9]  = fmaf(w, u2.y, acc[9]);
        acc[10] = fmaf(w, u2.z, acc[10]);  acc[11] = fmaf(w, u2.w, acc[11]);
        acc[12] = fmaf(w, u3.x, acc[12]);  acc[13] = fmaf(w, u3.y, acc[13]);
        acc[14] = fmaf(w, u3.z, acc[14]);  acc[15] = fmaf(w, u3.w, acc[15]);
    }
    float* o = out + (size_t)i * C_CH;
#pragma unroll
    for (int c = 0; c < C_CH; ++c) atomicAdd(&o[c], acc[c]);
}

extern "C" void kernel_launch(void* const* d_in, const int* in_sizes, int n_in,
                              void* d_out, int out_size, void* d_ws, size_t ws_size,
                              hipStream_t stream) {
    const float* U   = (const float*)d_in[0];   // [8192,16]
    const float* ref = (const float*)d_in[1];   // [8192,5]
    float* out       = (float*)d_out;           // [8192,16]

    const size_t refB_b = (size_t)N_ROWS * 64;              // 512 KB
    const size_t upk_b  = (size_t)C_CH * N_ROWS * 2;        // 256 KB each
    const size_t part_b = (size_t)NSEG * C_CH * N_ROWS * 4; // 8.4 MB
    const size_t need   = refB_b + 2 * upk_b + part_b;

    if (ws_size >= need) {
        unsigned* refB = (unsigned*)d_ws;
        unsigned* uph  = (unsigned*)((char*)d_ws + refB_b);
        unsigned* upl  = (unsigned*)((char*)d_ws + refB_b + upk_b);
        float* part    = (float*)((char*)d_ws + refB_b + 2 * upk_b);

        const int pre_threads = N_ROWS + C_CH * N_ROWS / 2;   // 73728
        hipLaunchKernelGGL(lg_pre, dim3(pre_threads / TPB), dim3(TPB), 0, stream,
                           U, ref, refB, uph, upl);
        hipLaunchKernelGGL(lg_mfma, dim3(NIB * NSEG), dim3(TPB), 0, stream,
                           ref, refB, uph, upl, part);
        hipLaunchKernelGGL(lg_reduce, dim3(N_ROWS * C_CH / TPB), dim3(TPB),
                           0, stream, U, part, out);
    } else {
        hipLaunchKernelGGL(lg_init, dim3((N_ROWS * C_CH + TPB - 1) / TPB), dim3(TPB),
                           0, stream, U, out);
        hipLaunchKernelGGL(lg_main_atomic, dim3((N_ROWS / TPB) * 32), dim3(TPB),
                           0, stream, U, ref, out);
    }
}